// Round 1
// baseline (2350.768 us; speedup 1.0000x reference)
//
#include <hip/hip_runtime.h>
#include <hip/hip_bf16.h>

#define HIDDEN 3072
#define INTER  8192
#define NTOK   8192   // B*S = 4*2048

typedef __attribute__((ext_vector_type(8))) short bf16x8;
typedef __attribute__((ext_vector_type(4))) float f32x4;

__device__ __forceinline__ void gload_lds16(const void* g, void* l) {
  __builtin_amdgcn_global_load_lds(
      (const __attribute__((address_space(1))) void*)g,
      (__attribute__((address_space(3))) void*)l, 16, 0, 0);
}

__device__ __forceinline__ unsigned short f2bf(float f) {
  unsigned int u = __builtin_bit_cast(unsigned int, f);
  u += 0x7fffu + ((u >> 16) & 1u);   // round-to-nearest-even
  return (unsigned short)(u >> 16);
}

// ---------------- conversion kernels ----------------

__global__ void cvt_f32_bf16(const float* __restrict__ in,
                             unsigned short* __restrict__ out, int n4) {
  int i = blockIdx.x * blockDim.x + threadIdx.x;
  if (i >= n4) return;
  float4 v = reinterpret_cast<const float4*>(in)[i];
  ushort4 o;
  o.x = f2bf(v.x); o.y = f2bf(v.y); o.z = f2bf(v.z); o.w = f2bf(v.w);
  reinterpret_cast<ushort4*>(out)[i] = o;
}

__global__ void cvt_i32_bf16(const int* __restrict__ in,
                             unsigned short* __restrict__ out, int n4) {
  int i = blockIdx.x * blockDim.x + threadIdx.x;
  if (i >= n4) return;
  int4 v = reinterpret_cast<const int4*>(in)[i];
  ushort4 o;
  o.x = f2bf((float)v.x); o.y = f2bf((float)v.y);
  o.z = f2bf((float)v.z); o.w = f2bf((float)v.w);
  reinterpret_cast<ushort4*>(out)[i] = o;
}

// ---------------- GEMM1 + SwiGLU (fused) ----------------
// h[m,n] = silu(gate[m,n]) * up[m,n]
// gate[m,n] = sgate[n] * sum_k X[m,k] * Wq[n,k]
// up[m,n]   = sup[n]   * sum_k X[m,k] * Wq[INTER+n,k]

__global__ __launch_bounds__(256) void gemm1_swiglu(
    const unsigned short* __restrict__ X,   // [NTOK][HIDDEN] bf16
    const unsigned short* __restrict__ W,   // [2*INTER][HIDDEN] bf16
    const float* __restrict__ scale,        // [2*INTER]
    unsigned short* __restrict__ H)         // [NTOK][INTER] bf16
{
  constexpr int K = HIDDEN;
  __shared__ unsigned short As[128 * 32];
  __shared__ unsigned short Bg[128 * 32];
  __shared__ unsigned short Bu[128 * 32];

  const int nbn = INTER / 128;              // 64
  const int nwg = (NTOK / 128) * nbn;       // 4096 (%8==0 -> simple swizzle ok)
  int bid = blockIdx.x;
  int wg = (bid & 7) * (nwg >> 3) + (bid >> 3);   // XCD-aware bijective swizzle
  const int bm = (wg / nbn) * 128;
  const int bn = (wg % nbn) * 128;

  const int tid  = threadIdx.x;
  const int lane = tid & 63;
  const int wid  = tid >> 6;
  const int wr = wid >> 1, wc = wid & 1;

  // staging: lane covers 16B; chunk = 16 rows x 32 cols bf16 = 1024 B
  const int srow  = lane >> 2;        // 0..15
  const int skoff = (lane & 3) * 8;   // bf16 elements 0,8,16,24

  // fragment indices
  const int frow = lane & 15;
  const int fk   = (lane >> 4) * 8;

  f32x4 accg[4][4] = {};
  f32x4 accu[4][4] = {};

  for (int k0 = 0; k0 < K; k0 += 32) {
    // 24 chunks total (A:0-7, Bg:8-15, Bu:16-23); wave w stages 6
#pragma unroll
    for (int i = 0; i < 6; ++i) {
      int c = wid * 6 + i;
      int t = c >> 3;
      int cc = c & 7;
      int row = cc * 16 + srow;
      const unsigned short* src;
      unsigned short* dst;
      if (t == 0) {
        src = X + (size_t)(bm + row) * K + k0 + skoff;
        dst = As + cc * 512;
      } else if (t == 1) {
        src = W + (size_t)(bn + row) * K + k0 + skoff;
        dst = Bg + cc * 512;
      } else {
        src = W + (size_t)(INTER + bn + row) * K + k0 + skoff;
        dst = Bu + cc * 512;
      }
      gload_lds16(src, dst);
    }
    __syncthreads();   // drains vmcnt before barrier (compiler-inserted)

    bf16x8 a[4], bg[4], bu[4];
#pragma unroll
    for (int m = 0; m < 4; ++m)
      a[m] = *(const bf16x8*)&As[(wr * 64 + m * 16 + frow) * 32 + fk];
#pragma unroll
    for (int n = 0; n < 4; ++n) {
      bg[n] = *(const bf16x8*)&Bg[(wc * 64 + n * 16 + frow) * 32 + fk];
      bu[n] = *(const bf16x8*)&Bu[(wc * 64 + n * 16 + frow) * 32 + fk];
    }
#pragma unroll
    for (int m = 0; m < 4; ++m)
#pragma unroll
      for (int n = 0; n < 4; ++n) {
        accg[m][n] = __builtin_amdgcn_mfma_f32_16x16x32_bf16(a[m], bg[n], accg[m][n], 0, 0, 0);
        accu[m][n] = __builtin_amdgcn_mfma_f32_16x16x32_bf16(a[m], bu[n], accu[m][n], 0, 0, 0);
      }
    __syncthreads();
  }

  // epilogue: C/D layout col=lane&15, row=(lane>>4)*4+j  [m89-verified]
  const int crow0 = (lane >> 4) * 4;
  const int ccol  = lane & 15;
#pragma unroll
  for (int n = 0; n < 4; ++n) {
    int col = bn + wc * 64 + n * 16 + ccol;
    float sg = scale[col];
    float su = scale[INTER + col];
#pragma unroll
    for (int m = 0; m < 4; ++m) {
#pragma unroll
      for (int j = 0; j < 4; ++j) {
        int row = bm + wr * 64 + m * 16 + crow0 + j;
        float g = accg[m][n][j] * sg;
        float u = accu[m][n][j] * su;
        float s = g / (1.0f + __expf(-g));     // silu(g)
        H[(size_t)row * INTER + col] = f2bf(u * s);
      }
    }
  }
}

// ---------------- GEMM2 ----------------
// out[m,h] = dscale[h] * sum_i Hb[m,i] * Wd[h,i]

__global__ __launch_bounds__(256) void gemm2(
    const unsigned short* __restrict__ Hb,  // [NTOK][INTER] bf16
    const unsigned short* __restrict__ W,   // [HIDDEN][INTER] bf16
    const float* __restrict__ scale,        // [HIDDEN]
    float* __restrict__ out)                // [NTOK][HIDDEN] f32
{
  constexpr int K = INTER;
  __shared__ unsigned short As[128 * 32];
  __shared__ unsigned short Bs[128 * 32];

  const int nbn = HIDDEN / 128;             // 24
  const int nwg = (NTOK / 128) * nbn;       // 1536 (%8==0)
  int bid = blockIdx.x;
  int wg = (bid & 7) * (nwg >> 3) + (bid >> 3);
  const int bm = (wg / nbn) * 128;
  const int bn = (wg % nbn) * 128;

  const int tid  = threadIdx.x;
  const int lane = tid & 63;
  const int wid  = tid >> 6;
  const int wr = wid >> 1, wc = wid & 1;

  const int srow  = lane >> 2;
  const int skoff = (lane & 3) * 8;
  const int frow = lane & 15;
  const int fk   = (lane >> 4) * 8;

  f32x4 acc[4][4] = {};

  for (int k0 = 0; k0 < K; k0 += 32) {
    // 16 chunks (A:0-7, B:8-15); wave w stages 4
#pragma unroll
    for (int i = 0; i < 4; ++i) {
      int c = wid * 4 + i;
      int t = c >> 3;
      int cc = c & 7;
      int row = cc * 16 + srow;
      const unsigned short* src;
      unsigned short* dst;
      if (t == 0) {
        src = Hb + (size_t)(bm + row) * K + k0 + skoff;
        dst = As + cc * 512;
      } else {
        src = W + (size_t)(bn + row) * K + k0 + skoff;
        dst = Bs + cc * 512;
      }
      gload_lds16(src, dst);
    }
    __syncthreads();

    bf16x8 a[4], b[4];
#pragma unroll
    for (int m = 0; m < 4; ++m)
      a[m] = *(const bf16x8*)&As[(wr * 64 + m * 16 + frow) * 32 + fk];
#pragma unroll
    for (int n = 0; n < 4; ++n)
      b[n] = *(const bf16x8*)&Bs[(wc * 64 + n * 16 + frow) * 32 + fk];
#pragma unroll
    for (int m = 0; m < 4; ++m)
#pragma unroll
      for (int n = 0; n < 4; ++n)
        acc[m][n] = __builtin_amdgcn_mfma_f32_16x16x32_bf16(a[m], b[n], acc[m][n], 0, 0, 0);
    __syncthreads();
  }

  const int crow0 = (lane >> 4) * 4;
  const int ccol  = lane & 15;
#pragma unroll
  for (int n = 0; n < 4; ++n) {
    int col = bn + wc * 64 + n * 16 + ccol;
    float sc = scale[col];
#pragma unroll
    for (int m = 0; m < 4; ++m) {
#pragma unroll
      for (int j = 0; j < 4; ++j) {
        int row = bm + wr * 64 + m * 16 + crow0 + j;
        out[(size_t)row * HIDDEN + col] = acc[m][n][j] * sc;
      }
    }
  }
}

// ---------------- launch ----------------

extern "C" void kernel_launch(void* const* d_in, const int* in_sizes, int n_in,
                              void* d_out, int out_size, void* d_ws, size_t ws_size,
                              hipStream_t stream) {
  (void)in_sizes; (void)n_in; (void)out_size; (void)ws_size;

  const float* hidden = (const float*)d_in[0];   // [NTOK][HIDDEN] f32
  const int*   guq    = (const int*)d_in[1];     // [2*INTER][HIDDEN] i32
  const float* gus    = (const float*)d_in[2];   // [2*INTER]
  const int*   dwq    = (const int*)d_in[3];     // [HIDDEN][INTER] i32
  const float* dsc    = (const float*)d_in[4];   // [HIDDEN]
  float* out = (float*)d_out;

  char* ws = (char*)d_ws;
  unsigned short* xb  = (unsigned short*)(ws);                      // 50,331,648 B
  unsigned short* wgu = (unsigned short*)(ws + 50331648ull);        // 100,663,296 B
  unsigned short* wd  = (unsigned short*)(ws + 150994944ull);       // 50,331,648 B
  unsigned short* hb  = (unsigned short*)(ws + 201326592ull);       // 134,217,728 B
  // total ws use: 335,544,320 B

  {
    int n4 = NTOK * HIDDEN / 4;
    cvt_f32_bf16<<<(n4 + 255) / 256, 256, 0, stream>>>(hidden, xb, n4);
  }
  {
    int n4 = 2 * INTER * HIDDEN / 4;
    cvt_i32_bf16<<<(n4 + 255) / 256, 256, 0, stream>>>(guq, wgu, n4);
  }
  {
    int n4 = HIDDEN * INTER / 4;
    cvt_i32_bf16<<<(n4 + 255) / 256, 256, 0, stream>>>(dwq, wd, n4);
  }

  gemm1_swiglu<<<(NTOK / 128) * (INTER / 128), 256, 0, stream>>>(xb, wgu, gus, hb);
  gemm2<<<(NTOK / 128) * (HIDDEN / 128), 256, 0, stream>>>(hb, wd, dsc, out);
}

// Round 2
// 1778.564 us; speedup vs baseline: 1.3217x; 1.3217x over previous
//
#include <hip/hip_runtime.h>
#include <hip/hip_bf16.h>

#define HIDDEN 3072
#define INTER  8192
#define NTOK   8192   // B*S = 4*2048

typedef __attribute__((ext_vector_type(8))) short bf16x8;
typedef __attribute__((ext_vector_type(4))) float f32x4;

__device__ __forceinline__ void gload_lds16(const void* g, void* l) {
  __builtin_amdgcn_global_load_lds(
      (const __attribute__((address_space(1))) void*)g,
      (__attribute__((address_space(3))) void*)l, 16, 0, 0);
}

__device__ __forceinline__ unsigned short f2bf(float f) {
  unsigned int u = __builtin_bit_cast(unsigned int, f);
  u += 0x7fffu + ((u >> 16) & 1u);   // round-to-nearest-even
  return (unsigned short)(u >> 16);
}

// ---------------- conversion kernels ----------------

__global__ void cvt_f32_bf16(const float* __restrict__ in,
                             unsigned short* __restrict__ out, int n4) {
  int i = blockIdx.x * blockDim.x + threadIdx.x;
  if (i >= n4) return;
  float4 v = reinterpret_cast<const float4*>(in)[i];
  ushort4 o;
  o.x = f2bf(v.x); o.y = f2bf(v.y); o.z = f2bf(v.z); o.w = f2bf(v.w);
  reinterpret_cast<ushort4*>(out)[i] = o;
}

__global__ void cvt_i32_bf16(const int* __restrict__ in,
                             unsigned short* __restrict__ out, int n4) {
  int i = blockIdx.x * blockDim.x + threadIdx.x;
  if (i >= n4) return;
  int4 v = reinterpret_cast<const int4*>(in)[i];
  ushort4 o;
  o.x = f2bf((float)v.x); o.y = f2bf((float)v.y);
  o.z = f2bf((float)v.z); o.w = f2bf((float)v.w);
  reinterpret_cast<ushort4*>(out)[i] = o;
}

// ---------------- GEMM1 + SwiGLU (fused) ----------------
// Block tile: 128 rows (tokens) x 64 h-cols. Per wave: 64x32 h-tile,
// acc = accg[4][2] + accu[4][2] = 64 regs total -> 3 waves/SIMD occupancy.

__global__ __launch_bounds__(256, 3) void gemm1_swiglu(
    const unsigned short* __restrict__ X,   // [NTOK][HIDDEN] bf16
    const unsigned short* __restrict__ W,   // [2*INTER][HIDDEN] bf16
    const float* __restrict__ scale,        // [2*INTER]
    unsigned short* __restrict__ H)         // [NTOK][INTER] bf16
{
  constexpr int K = HIDDEN;
  __shared__ unsigned short As[128 * 32];   // 8 KB
  __shared__ unsigned short Bg[64 * 32];    // 4 KB
  __shared__ unsigned short Bu[64 * 32];    // 4 KB

  const int nbn = INTER / 64;               // 128
  const int nwg = (NTOK / 128) * nbn;       // 8192 (%8==0 -> bijective swizzle)
  int bid = blockIdx.x;
  int wg = (bid & 7) * (nwg >> 3) + (bid >> 3);   // XCD-aware swizzle
  const int bm = (wg / nbn) * 128;
  const int bn = (wg % nbn) * 64;

  const int tid  = threadIdx.x;
  const int lane = tid & 63;
  const int wid  = tid >> 6;
  const int wr = wid >> 1, wc = wid & 1;    // 2M x 2N wave grid

  // staging: lane covers 16B; chunk = 16 rows x 32 cols bf16 = 1024 B
  const int srow  = lane >> 2;        // 0..15
  const int skoff = (lane & 3) * 8;   // bf16 elements 0,8,16,24

  // fragment indices
  const int frow = lane & 15;
  const int fk   = (lane >> 4) * 8;

  f32x4 accg[4][2] = {};
  f32x4 accu[4][2] = {};

  for (int k0 = 0; k0 < K; k0 += 32) {
    // 16 chunks total (A:0-7, Bg:8-11, Bu:12-15); wave w stages 4
#pragma unroll
    for (int i = 0; i < 4; ++i) {
      int c = wid * 4 + i;
      const unsigned short* src;
      unsigned short* dst;
      if (c < 8) {
        src = X + (size_t)(bm + c * 16 + srow) * K + k0 + skoff;
        dst = As + c * 512;
      } else if (c < 12) {
        int cc = c - 8;
        src = W + (size_t)(bn + cc * 16 + srow) * K + k0 + skoff;
        dst = Bg + cc * 512;
      } else {
        int cc = c - 12;
        src = W + (size_t)(INTER + bn + cc * 16 + srow) * K + k0 + skoff;
        dst = Bu + cc * 512;
      }
      gload_lds16(src, dst);
    }
    __syncthreads();

    bf16x8 a[4], bg[2], bu[2];
#pragma unroll
    for (int m = 0; m < 4; ++m)
      a[m] = *(const bf16x8*)&As[(wr * 64 + m * 16 + frow) * 32 + fk];
#pragma unroll
    for (int n = 0; n < 2; ++n) {
      bg[n] = *(const bf16x8*)&Bg[(wc * 32 + n * 16 + frow) * 32 + fk];
      bu[n] = *(const bf16x8*)&Bu[(wc * 32 + n * 16 + frow) * 32 + fk];
    }
#pragma unroll
    for (int m = 0; m < 4; ++m)
#pragma unroll
      for (int n = 0; n < 2; ++n) {
        accg[m][n] = __builtin_amdgcn_mfma_f32_16x16x32_bf16(a[m], bg[n], accg[m][n], 0, 0, 0);
        accu[m][n] = __builtin_amdgcn_mfma_f32_16x16x32_bf16(a[m], bu[n], accu[m][n], 0, 0, 0);
      }
    __syncthreads();
  }

  // epilogue: C/D layout col=lane&15, row=(lane>>4)*4+j  [m89-verified]
  const int crow0 = (lane >> 4) * 4;
  const int ccol  = lane & 15;
#pragma unroll
  for (int n = 0; n < 2; ++n) {
    int col = bn + wc * 32 + n * 16 + ccol;
    float sg = scale[col];
    float su = scale[INTER + col];
#pragma unroll
    for (int m = 0; m < 4; ++m) {
#pragma unroll
      for (int j = 0; j < 4; ++j) {
        int row = bm + wr * 64 + m * 16 + crow0 + j;
        float g = accg[m][n][j] * sg;
        float u = accu[m][n][j] * su;
        float s = g / (1.0f + __expf(-g));     // silu(g)
        H[(size_t)row * INTER + col] = f2bf(u * s);
      }
    }
  }
}

// ---------------- GEMM2 ----------------
// out[m,h] = dscale[h] * sum_i Hb[m,i] * Wd[h,i]

__global__ __launch_bounds__(256) void gemm2(
    const unsigned short* __restrict__ Hb,  // [NTOK][INTER] bf16
    const unsigned short* __restrict__ W,   // [HIDDEN][INTER] bf16
    const float* __restrict__ scale,        // [HIDDEN]
    float* __restrict__ out)                // [NTOK][HIDDEN] f32
{
  constexpr int K = INTER;
  __shared__ unsigned short As[128 * 32];
  __shared__ unsigned short Bs[128 * 32];

  const int nbn = HIDDEN / 128;             // 24
  const int nwg = (NTOK / 128) * nbn;       // 1536 (%8==0)
  int bid = blockIdx.x;
  int wg = (bid & 7) * (nwg >> 3) + (bid >> 3);
  const int bm = (wg / nbn) * 128;
  const int bn = (wg % nbn) * 128;

  const int tid  = threadIdx.x;
  const int lane = tid & 63;
  const int wid  = tid >> 6;
  const int wr = wid >> 1, wc = wid & 1;

  const int srow  = lane >> 2;
  const int skoff = (lane & 3) * 8;
  const int frow = lane & 15;
  const int fk   = (lane >> 4) * 8;

  f32x4 acc[4][4] = {};

  for (int k0 = 0; k0 < K; k0 += 32) {
    // 16 chunks (A:0-7, B:8-15); wave w stages 4
#pragma unroll
    for (int i = 0; i < 4; ++i) {
      int c = wid * 4 + i;
      int t = c >> 3;
      int cc = c & 7;
      int row = cc * 16 + srow;
      const unsigned short* src;
      unsigned short* dst;
      if (t == 0) {
        src = Hb + (size_t)(bm + row) * K + k0 + skoff;
        dst = As + cc * 512;
      } else {
        src = W + (size_t)(bn + row) * K + k0 + skoff;
        dst = Bs + cc * 512;
      }
      gload_lds16(src, dst);
    }
    __syncthreads();

    bf16x8 a[4], b[4];
#pragma unroll
    for (int m = 0; m < 4; ++m)
      a[m] = *(const bf16x8*)&As[(wr * 64 + m * 16 + frow) * 32 + fk];
#pragma unroll
    for (int n = 0; n < 4; ++n)
      b[n] = *(const bf16x8*)&Bs[(wc * 64 + n * 16 + frow) * 32 + fk];
#pragma unroll
    for (int m = 0; m < 4; ++m)
#pragma unroll
      for (int n = 0; n < 4; ++n)
        acc[m][n] = __builtin_amdgcn_mfma_f32_16x16x32_bf16(a[m], b[n], acc[m][n], 0, 0, 0);
    __syncthreads();
  }

  const int crow0 = (lane >> 4) * 4;
  const int ccol  = lane & 15;
#pragma unroll
  for (int n = 0; n < 4; ++n) {
    int col = bn + wc * 64 + n * 16 + ccol;
    float sc = scale[col];
#pragma unroll
    for (int m = 0; m < 4; ++m) {
#pragma unroll
      for (int j = 0; j < 4; ++j) {
        int row = bm + wr * 64 + m * 16 + crow0 + j;
        out[(size_t)row * HIDDEN + col] = acc[m][n][j] * sc;
      }
    }
  }
}

// ---------------- launch ----------------

extern "C" void kernel_launch(void* const* d_in, const int* in_sizes, int n_in,
                              void* d_out, int out_size, void* d_ws, size_t ws_size,
                              hipStream_t stream) {
  (void)in_sizes; (void)n_in; (void)out_size; (void)ws_size;

  const float* hidden = (const float*)d_in[0];   // [NTOK][HIDDEN] f32
  const int*   guq    = (const int*)d_in[1];     // [2*INTER][HIDDEN] i32
  const float* gus    = (const float*)d_in[2];   // [2*INTER]
  const int*   dwq    = (const int*)d_in[3];     // [HIDDEN][INTER] i32
  const float* dsc    = (const float*)d_in[4];   // [HIDDEN]
  float* out = (float*)d_out;

  char* ws = (char*)d_ws;
  unsigned short* xb  = (unsigned short*)(ws);                      // 50,331,648 B
  unsigned short* wgu = (unsigned short*)(ws + 50331648ull);        // 100,663,296 B
  unsigned short* wd  = (unsigned short*)(ws + 150994944ull);       // 50,331,648 B
  unsigned short* hb  = (unsigned short*)(ws + 201326592ull);       // 134,217,728 B
  // total ws use: 335,544,320 B

  {
    int n4 = NTOK * HIDDEN / 4;
    cvt_f32_bf16<<<(n4 + 255) / 256, 256, 0, stream>>>(hidden, xb, n4);
  }
  {
    int n4 = 2 * INTER * HIDDEN / 4;
    cvt_i32_bf16<<<(n4 + 255) / 256, 256, 0, stream>>>(guq, wgu, n4);
  }
  {
    int n4 = HIDDEN * INTER / 4;
    cvt_i32_bf16<<<(n4 + 255) / 256, 256, 0, stream>>>(dwq, wd, n4);
  }

  gemm1_swiglu<<<(NTOK / 128) * (INTER / 64), 256, 0, stream>>>(xb, wgu, gus, hb);
  gemm2<<<(NTOK / 128) * (HIDDEN / 128), 256, 0, stream>>>(hb, wd, dsc, out);
}

// Round 4
// 1303.600 us; speedup vs baseline: 1.8033x; 1.3643x over previous
//
#include <hip/hip_runtime.h>
#include <hip/hip_bf16.h>

#define HIDDEN 3072
#define INTER  8192
#define NTOK   8192   // B*S = 4*2048

typedef __attribute__((ext_vector_type(8))) short bf16x8;
typedef __attribute__((ext_vector_type(4))) float f32x4;

__device__ __forceinline__ void gload_lds16(const void* g, void* l) {
  __builtin_amdgcn_global_load_lds(
      (const __attribute__((address_space(1))) void*)g,
      (__attribute__((address_space(3))) void*)l, 16, 0, 0);
}

__device__ __forceinline__ unsigned short f2bf(float f) {
  unsigned int u = __builtin_bit_cast(unsigned int, f);
  u += 0x7fffu + ((u >> 16) & 1u);   // round-to-nearest-even
  return (unsigned short)(u >> 16);
}

// ---------------- conversion kernels ----------------

__global__ void cvt_f32_bf16(const float* __restrict__ in,
                             unsigned short* __restrict__ out, int n4) {
  int i = blockIdx.x * blockDim.x + threadIdx.x;
  if (i >= n4) return;
  float4 v = reinterpret_cast<const float4*>(in)[i];
  ushort4 o;
  o.x = f2bf(v.x); o.y = f2bf(v.y); o.z = f2bf(v.z); o.w = f2bf(v.w);
  reinterpret_cast<ushort4*>(out)[i] = o;
}

__global__ void cvt_i32_bf16(const int* __restrict__ in,
                             unsigned short* __restrict__ out, int n4) {
  int i = blockIdx.x * blockDim.x + threadIdx.x;
  if (i >= n4) return;
  int4 v = reinterpret_cast<const int4*>(in)[i];
  ushort4 o;
  o.x = f2bf((float)v.x); o.y = f2bf((float)v.y);
  o.z = f2bf((float)v.z); o.w = f2bf((float)v.w);
  reinterpret_cast<ushort4*>(out)[i] = o;
}

// W_gu convert with gate/up row interleave:
// W'-row rowp = 32*(c>>4) + 16*u + (c&15)  for h-col c, u=0 gate / 1 up.
// So a 64-col wave tile contains n-frags (gate c.., up c.., gate c+16.., up c+16..).
__global__ void cvt_wgu_perm(const int* __restrict__ in,
                             unsigned short* __restrict__ out) {
  int i4 = blockIdx.x * blockDim.x + threadIdx.x;
  const int RW = HIDDEN / 4;   // 768 int4-groups per row
  if (i4 >= 2 * INTER * RW) return;
  int rowp = i4 / RW;
  int col4 = i4 - rowp * RW;
  int c = ((rowp >> 5) << 4) + (rowp & 15);
  int u = (rowp >> 4) & 1;
  int srow = u * INTER + c;
  int4 v = reinterpret_cast<const int4*>(in)[(size_t)srow * RW + col4];
  ushort4 o;
  o.x = f2bf((float)v.x); o.y = f2bf((float)v.y);
  o.z = f2bf((float)v.z); o.w = f2bf((float)v.w);
  reinterpret_cast<ushort4*>(out)[i4] = o;
}

// ---------------- 256x256 8-phase GEMM (T2+T3+T4+T5) ----------------
// C = A[M=8192][K] * B[N][K]^T, bf16 in, fp32 acc.
// 512 threads = 8 waves (2M x 4N). Per wave: 128x64 output = acc[8][4] f32x4.
// LDS: [parity][op A/B][k-half][256 rows][32 cols] bf16 = 128 KiB total.
// vmcnt ledger (per-wave, 2 gload_lds per stage):
//   tile-t entry invariant: 4 outstanding = {A(t)kh1, B(t)kh1}; kh0 landed.
//   P2-end: outstanding 8 -> vmcnt(4) drains t's kh1 (needed by P3).
//     *** TAIL FIX (round-3 race): on t==NT-1, stage(NT) no-ops so only 4
//     outstanding -> vmcnt(4) was a NO-OP and P3 read un-landed kh1. Use
//     vmcnt(0) on the final tile. ***
//   P4-end: outstanding 8 -> vmcnt(4) drains (t+1)'s kh0 (needed next P1).

template<int K, int N, bool SWIGLU>
__global__ __launch_bounds__(512, 2) void gemm8p(
    const unsigned short* __restrict__ A,   // [NTOK][K]
    const unsigned short* __restrict__ B,   // [N][K]
    const float* __restrict__ scale,
    void* __restrict__ outv)
{
  constexpr int NT = K / 64;
  __shared__ __align__(16) unsigned short lds[2][2][2][256 * 32];

  const int nbn = N / 256;
  const int nwg = (NTOK / 256) * nbn;       // %8 == 0 for both instantiations
  int bid = blockIdx.x;
  int wg = (bid & 7) * (nwg >> 3) + (bid >> 3);   // XCD-aware bijective swizzle
  const int bm = (wg / nbn) * 256;
  const int bn = (wg % nbn) * 256;

  const int tid  = threadIdx.x;
  const int lane = tid & 63;
  const int wid  = tid >> 6;
  const int wr = wid >> 2;                  // 0..1
  const int wc = wid & 3;                   // 0..3

  // staging coords: chunk = inst*512 + tid; row = chunk>>2, cb = chunk&3
  const int srow0 = tid >> 2;               // rows 0..127 (inst 0)
  const int srow1 = 128 + (tid >> 2);       // rows 128..255 (inst 1)
  const int scb   = tid & 3;

  const unsigned short* Ab = A + (size_t)bm * K;
  const unsigned short* Bb = B + (size_t)bn * K;

  auto stage = [&](const unsigned short* Gb, int op, int tt, int kh) {
    if (tt >= NT) return;
    int p = tt & 1;
    int kc = tt * 64 + kh * 32;
    unsigned short* lbase = &lds[p][op][kh][0];
    gload_lds16(Gb + (size_t)srow0 * K + kc + ((scb ^ (srow0 & 3)) * 8),
                lbase + (size_t)tid * 8);
    gload_lds16(Gb + (size_t)srow1 * K + kc + ((scb ^ (srow1 & 3)) * 8),
                lbase + (size_t)(512 + tid) * 8);
  };

  auto readA = [&](int p, int kh, int m) -> bf16x8 {
    int row = wr * 128 + m * 16 + (lane & 15);
    int cb = (lane >> 4) ^ (row & 3);
    return *(const bf16x8*)&lds[p][0][kh][row * 32 + cb * 8];
  };
  auto readB = [&](int p, int kh, int n) -> bf16x8 {
    int row = wc * 64 + n * 16 + (lane & 15);
    int cb = (lane >> 4) ^ (row & 3);
    return *(const bf16x8*)&lds[p][1][kh][row * 32 + cb * 8];
  };

  f32x4 acc[8][4] = {};
  bf16x8 af[8];

  // prologue: tile 0's 4 half-tiles; vmcnt(4) -> A-kh0, B-kh0 landed
  stage(Ab, 0, 0, 0);
  stage(Bb, 1, 0, 0);
  stage(Ab, 0, 0, 1);
  stage(Bb, 1, 0, 1);
  asm volatile("s_waitcnt vmcnt(4)" ::: "memory");
  __builtin_amdgcn_s_barrier();

  for (int t = 0; t < NT; ++t) {
    const int pr = t & 1;
    // ---- phase 1: kh0, n-frags 0,1 ----
#pragma unroll
    for (int m = 0; m < 8; ++m) af[m] = readA(pr, 0, m);
    bf16x8 b0 = readB(pr, 0, 0);
    bf16x8 b1 = readB(pr, 0, 1);
    stage(Ab, 0, t + 1, 0);
    __builtin_amdgcn_s_barrier();
    __builtin_amdgcn_s_setprio(1);
#pragma unroll
    for (int m = 0; m < 8; ++m) {
      acc[m][0] = __builtin_amdgcn_mfma_f32_16x16x32_bf16(af[m], b0, acc[m][0], 0, 0, 0);
      acc[m][1] = __builtin_amdgcn_mfma_f32_16x16x32_bf16(af[m], b1, acc[m][1], 0, 0, 0);
    }
    __builtin_amdgcn_s_setprio(0);
    __builtin_amdgcn_s_barrier();

    // ---- phase 2: kh0, n-frags 2,3 ----
    b0 = readB(pr, 0, 2);
    b1 = readB(pr, 0, 3);
    stage(Bb, 1, t + 1, 0);
    __builtin_amdgcn_s_barrier();
    __builtin_amdgcn_s_setprio(1);
#pragma unroll
    for (int m = 0; m < 8; ++m) {
      acc[m][2] = __builtin_amdgcn_mfma_f32_16x16x32_bf16(af[m], b0, acc[m][2], 0, 0, 0);
      acc[m][3] = __builtin_amdgcn_mfma_f32_16x16x32_bf16(af[m], b1, acc[m][3], 0, 0, 0);
    }
    __builtin_amdgcn_s_setprio(0);
    // TAIL FIX: final tile has no t+1 stages in flight -> must drain to 0
    // so this tile's kh1 halves are guaranteed landed before phase 3 reads.
    if (t + 1 < NT) {
      asm volatile("s_waitcnt vmcnt(4)" ::: "memory");
    } else {
      asm volatile("s_waitcnt vmcnt(0)" ::: "memory");
    }
    __builtin_amdgcn_s_barrier();

    // ---- phase 3: kh1, n-frags 0,1 ----
#pragma unroll
    for (int m = 0; m < 8; ++m) af[m] = readA(pr, 1, m);
    b0 = readB(pr, 1, 0);
    b1 = readB(pr, 1, 1);
    stage(Ab, 0, t + 1, 1);
    __builtin_amdgcn_s_barrier();
    __builtin_amdgcn_s_setprio(1);
#pragma unroll
    for (int m = 0; m < 8; ++m) {
      acc[m][0] = __builtin_amdgcn_mfma_f32_16x16x32_bf16(af[m], b0, acc[m][0], 0, 0, 0);
      acc[m][1] = __builtin_amdgcn_mfma_f32_16x16x32_bf16(af[m], b1, acc[m][1], 0, 0, 0);
    }
    __builtin_amdgcn_s_setprio(0);
    __builtin_amdgcn_s_barrier();

    // ---- phase 4: kh1, n-frags 2,3 ----
    b0 = readB(pr, 1, 2);
    b1 = readB(pr, 1, 3);
    stage(Bb, 1, t + 1, 1);
    __builtin_amdgcn_s_barrier();
    __builtin_amdgcn_s_setprio(1);
#pragma unroll
    for (int m = 0; m < 8; ++m) {
      acc[m][2] = __builtin_amdgcn_mfma_f32_16x16x32_bf16(af[m], b0, acc[m][2], 0, 0, 0);
      acc[m][3] = __builtin_amdgcn_mfma_f32_16x16x32_bf16(af[m], b1, acc[m][3], 0, 0, 0);
    }
    __builtin_amdgcn_s_setprio(0);
    asm volatile("s_waitcnt vmcnt(4)" ::: "memory");   // drains tile t+1's kh0 (no-op on last tile: 0 outstanding)
    __builtin_amdgcn_s_barrier();
  }

  // ---- epilogue: C/D layout col=lane&15, row=(lane>>4)*4+j ----
  const int crow0 = (lane >> 4) * 4;
  const int ccol  = lane & 15;
  if constexpr (SWIGLU) {
    unsigned short* H = (unsigned short*)outv;     // [NTOK][INTER]
    const int hbase = (bn >> 1) + wc * 32;
#pragma unroll
    for (int np = 0; np < 2; ++np) {
      int hcol = hbase + np * 16 + ccol;
      float sg = scale[hcol];
      float su = scale[INTER + hcol];
#pragma unroll
      for (int m = 0; m < 8; ++m) {
#pragma unroll
        for (int j = 0; j < 4; ++j) {
          int row = bm + wr * 128 + m * 16 + crow0 + j;
          float g = acc[m][2 * np + 0][j] * sg;
          float u = acc[m][2 * np + 1][j] * su;
          float s = g / (1.0f + __expf(-g));       // silu
          H[(size_t)row * INTER + hcol] = f2bf(u * s);
        }
      }
    }
  } else {
    float* O = (float*)outv;                       // [NTOK][N]
#pragma unroll
    for (int n = 0; n < 4; ++n) {
      int col = bn + wc * 64 + n * 16 + ccol;
      float sc = scale[col];
#pragma unroll
      for (int m = 0; m < 8; ++m) {
#pragma unroll
        for (int j = 0; j < 4; ++j) {
          int row = bm + wr * 128 + m * 16 + crow0 + j;
          O[(size_t)row * N + col] = acc[m][n][j] * sc;
        }
      }
    }
  }
}

// ---------------- launch ----------------

extern "C" void kernel_launch(void* const* d_in, const int* in_sizes, int n_in,
                              void* d_out, int out_size, void* d_ws, size_t ws_size,
                              hipStream_t stream) {
  (void)in_sizes; (void)n_in; (void)out_size; (void)ws_size;

  const float* hidden = (const float*)d_in[0];   // [NTOK][HIDDEN] f32
  const int*   guq    = (const int*)d_in[1];     // [2*INTER][HIDDEN] i32
  const float* gus    = (const float*)d_in[2];   // [2*INTER]
  const int*   dwq    = (const int*)d_in[3];     // [HIDDEN][INTER] i32
  const float* dsc    = (const float*)d_in[4];   // [HIDDEN]
  float* out = (float*)d_out;

  char* ws = (char*)d_ws;
  unsigned short* xb  = (unsigned short*)(ws);                      // 50,331,648 B
  unsigned short* wgu = (unsigned short*)(ws + 50331648ull);        // 100,663,296 B (permuted)
  unsigned short* wd  = (unsigned short*)(ws + 150994944ull);       // 50,331,648 B
  unsigned short* hb  = (unsigned short*)(ws + 201326592ull);       // 134,217,728 B
  // total ws use: 335,544,320 B

  {
    int n4 = NTOK * HIDDEN / 4;
    cvt_f32_bf16<<<(n4 + 255) / 256, 256, 0, stream>>>(hidden, xb, n4);
  }
  {
    int n4 = 2 * INTER * HIDDEN / 4;
    cvt_wgu_perm<<<(n4 + 255) / 256, 256, 0, stream>>>(guq, wgu);
  }
  {
    int n4 = HIDDEN * INTER / 4;
    cvt_i32_bf16<<<(n4 + 255) / 256, 256, 0, stream>>>(dwq, wd, n4);
  }

  // GEMM1+SwiGLU: [8192 x 16384] over K=3072, writes H bf16 [8192][8192]
  gemm8p<HIDDEN, 2 * INTER, true>
      <<<(NTOK / 256) * (2 * INTER / 256), 512, 0, stream>>>(xb, wgu, gus, hb);
  // GEMM2: [8192 x 3072] over K=8192, writes out f32
  gemm8p<INTER, HIDDEN, false>
      <<<(NTOK / 256) * (HIDDEN / 256), 512, 0, stream>>>(hb, wd, dsc, out);
}